// Round 12
// baseline (722.655 us; speedup 1.0000x reference)
//
#include <hip/hip_runtime.h>
#include <hip/hip_bf16.h>
#include <math.h>

#define D_ 256
#define S_ 2048
#define B_ 4
#define H_ 8
#define HD_ 32
#define MLP_ 1024
#define L_ 4
#define M_ 256
#define NNZ 192
#define ROWS 8192   // S*B

typedef __attribute__((ext_vector_type(8))) short bf16x8;
typedef __attribute__((ext_vector_type(8))) unsigned short u16x8;
typedef __attribute__((ext_vector_type(4))) float f32x4;
typedef __attribute__((ext_vector_type(4))) int i32x4;

__device__ __forceinline__ unsigned short f2bf(float f) {
    union { float f; unsigned u; } c; c.f = f;
    unsigned r = (c.u + 0x7FFFu + ((c.u >> 16) & 1u)) >> 16;   // RNE
    return (unsigned short)r;
}
__device__ __forceinline__ float bf2f(unsigned short u) {
    union { unsigned u; float f; } c; c.u = (unsigned)u << 16;
    return c.f;
}

// async global->LDS, 16B per lane; lds dst = wave-uniform base + lane*16
#define GLOAD16(gsrc, ldst) __builtin_amdgcn_global_load_lds( \
    (const __attribute__((address_space(1))) unsigned int*)(gsrc), \
    (__attribute__((address_space(3))) unsigned int*)(ldst), 16, 0, 0)

// ---------------- mask dtype detection (parallel) ----------------
__global__ __launch_bounds__(256) void detect_mask_kernel(const unsigned int* __restrict__ mask,
                                                          int* __restrict__ flag) {
    int i = blockIdx.x * 256 + threadIdx.x;    // 4096 uint4 = 64KB
    uint4 v = *(const uint4*)&mask[i * 4];
    bool hit = ((v.x | v.y | v.z | v.w) & 0x0000FF00u) != 0;
    if (__ballot(hit)) {
        if ((threadIdx.x & 63) == 0) atomicOr(flag, 1);
        else if (hit) atomicOr(flag, 1);
    }
}

// ---------------- mask compaction ----------------
__global__ __launch_bounds__(256) void build_idx_kernel(const void* __restrict__ mask,
                                                        int* __restrict__ idx,
                                                        const int* __restrict__ flagp) {
    int wave = threadIdx.x >> 6, lane = threadIdx.x & 63;
    int row = blockIdx.x * 4 + wave;
    int isbyte = *flagp;
    const unsigned char* mb = (const unsigned char*)mask;
    const int* mi = (const int*)mask;
    int base = 0;
    for (int c = 0; c < S_ / 64; c++) {
        int t = c * 64 + lane;
        size_t off = (size_t)row * S_ + t;
        bool bit = isbyte ? (mb[off] != 0) : (mi[off] != 0);
        unsigned long long bm = __ballot(bit);
        if (bit) {
            int pos = base + __popcll(bm & ((1ull << lane) - 1ull));
            if (pos < NNZ) idx[row * NNZ + pos] = t;
        }
        base += __popcll(bm);
    }
}

// ---------------- all weights f32 -> bf16, one launch ----------------
__global__ __launch_bounds__(256) void cvt_all_kernel(const float* __restrict__ in_w,
                                                      const float* __restrict__ out_w,
                                                      const float* __restrict__ w1,
                                                      const float* __restrict__ w2,
                                                      unsigned short* __restrict__ in_w_bf,
                                                      unsigned short* __restrict__ out_w_bf,
                                                      unsigned short* __restrict__ w1_bf,
                                                      unsigned short* __restrict__ w2_bf) {
    int i = blockIdx.x * 256 + threadIdx.x;
    const float* src; unsigned short* dst; int off;
    if (i < 196608)      { src = in_w;  dst = in_w_bf;  off = i; }
    else if (i < 262144) { src = out_w; dst = out_w_bf; off = i - 196608; }
    else if (i < 524288) { src = w1;    dst = w1_bf;    off = i - 262144; }
    else                 { src = w2;    dst = w2_bf;    off = i - 524288; }
    float4 v = *(const float4*)&src[(size_t)off * 4];
    ushort4 o;
    o.x = f2bf(v.x); o.y = f2bf(v.y); o.z = f2bf(v.z); o.w = f2bf(v.w);
    *(ushort4*)&dst[(size_t)off * 4] = o;
}

// ---------------- embedding + sinusoidal positional encoding ----------------
__global__ __launch_bounds__(256) void embed_kernel(const int* __restrict__ x,
                                                    const float* __restrict__ emb,
                                                    float* __restrict__ h) {
    int e = blockIdx.x * 256 + threadIdx.x;
    int r = e >> 7, i = e & 127;
    int s = r >> 2, b = r & 3;
    int tok = x[b * S_ + s];
    float div = expf(-(float)(2 * i) * (9.210340371976184f / 256.0f));
    float ang = (float)s * div;
    float sv = sinf(ang), cv = cosf(ang);
    float2 ev = *(const float2*)&emb[(size_t)tok * D_ + 2 * i];
    float2 hv;
    hv.x = ev.x * 16.0f + sv;
    hv.y = ev.y * 16.0f + cv;
    *(float2*)&h[(size_t)r * D_ + 2 * i] = hv;
}

// ---------------- LayerNorm: one wave per row, bf16 out ----------------
__global__ __launch_bounds__(256) void ln_kernel(const float* __restrict__ x,
                                                 const float* __restrict__ g,
                                                 const float* __restrict__ b,
                                                 unsigned short* __restrict__ o) {
    int row = blockIdx.x * 4 + (threadIdx.x >> 6);
    int lane = threadIdx.x & 63;
    float4 v = *(const float4*)&x[(size_t)row * D_ + lane * 4];
    float s = v.x + v.y + v.z + v.w;
    float ss = v.x * v.x + v.y * v.y + v.z * v.z + v.w * v.w;
#pragma unroll
    for (int off = 32; off; off >>= 1) {
        s += __shfl_xor(s, off, 64);
        ss += __shfl_xor(ss, off, 64);
    }
    float mu = s * (1.0f / 256.0f);
    float var = ss * (1.0f / 256.0f) - mu * mu;
    float rstd = rsqrtf(var + 1e-5f);
    float4 gv = *(const float4*)&g[lane * 4];
    float4 bv = *(const float4*)&b[lane * 4];
    ushort4 ov;
    ov.x = f2bf((v.x - mu) * rstd * gv.x + bv.x);
    ov.y = f2bf((v.y - mu) * rstd * gv.y + bv.y);
    ov.z = f2bf((v.z - mu) * rstd * gv.z + bv.z);
    ov.w = f2bf((v.w - mu) * rstd * gv.w + bv.w);
    *(ushort4*)&o[(size_t)row * D_ + lane * 4] = ov;
}

// ---------------- bf16 MFMA GEMM v2: m97 structure ----------------
// 128x128 tile, BK=32, 4 waves in 2x2 (each 64x64 = 4x4 frags, 16 MFMA/K-step).
// Staging via global_load_lds width-16 into LINEAR LDS [row][32].
// Per call-site: each wave writes a 1KB chunk (16 rows); lane l -> row l/4, gran l%4.
#define GBM 128
#define GBN 128
#define GBK 32

template<int OUT_BF16>
__global__ __launch_bounds__(256) void gemm_bf16_v2(const unsigned short* __restrict__ A,
                                                    const unsigned short* __restrict__ W,
                                                    const float* __restrict__ bias,
                                                    const float* __restrict__ res,
                                                    void* __restrict__ Cp,
                                                    int N, int K) {
    __shared__ unsigned short As[GBM * GBK];   // 8 KB
    __shared__ unsigned short Ws[GBN * GBK];   // 8 KB
    int tid = threadIdx.x;
    int m0 = blockIdx.y * GBM, n0 = blockIdx.x * GBN;
    int w = tid >> 6, l = tid & 63;
    int wr = (w >> 1) * 64, wc = (w & 1) * 64;
    int rl = l & 15, koff = (l >> 4) * 8;

    f32x4 acc[4][4];
#pragma unroll
    for (int mi = 0; mi < 4; mi++)
#pragma unroll
        for (int ni = 0; ni < 4; ni++) acc[mi][ni] = (f32x4){0.f, 0.f, 0.f, 0.f};

    int crow = l >> 2;            // row within 16-row chunk
    int cgr = (l & 3) * 8;        // element offset within row (granule*8)

    for (int kt = 0; kt < K; kt += GBK) {
        __syncthreads();   // previous iteration's frag reads complete
#pragma unroll
        for (int c = 0; c < 2; c++) {
            int rbase = (w * 2 + c) * 16;   // wave-uniform chunk base row
            GLOAD16(&A[(size_t)(m0 + rbase + crow) * K + kt + cgr], &As[rbase * GBK]);
            GLOAD16(&W[(size_t)(n0 + rbase + crow) * K + kt + cgr], &Ws[rbase * GBK]);
        }
        __syncthreads();   // vmcnt drained by compiler before barrier -> LDS ready
        bf16x8 af[4], wf[4];
#pragma unroll
        for (int mi = 0; mi < 4; mi++)
            af[mi] = *(const bf16x8*)&As[(wr + mi * 16 + rl) * GBK + koff];
#pragma unroll
        for (int ni = 0; ni < 4; ni++)
            wf[ni] = *(const bf16x8*)&Ws[(wc + ni * 16 + rl) * GBK + koff];
#pragma unroll
        for (int mi = 0; mi < 4; mi++)
#pragma unroll
            for (int ni = 0; ni < 4; ni++)
                acc[mi][ni] = __builtin_amdgcn_mfma_f32_16x16x32_bf16(af[mi], wf[ni], acc[mi][ni], 0, 0, 0);
    }

    int col = l & 15, rbase2 = (l >> 4) * 4;
#pragma unroll
    for (int mi = 0; mi < 4; mi++) {
#pragma unroll
        for (int ni = 0; ni < 4; ni++) {
            int c = n0 + wc + ni * 16 + col;
            float bv = bias[c];
#pragma unroll
            for (int j = 0; j < 4; j++) {
                int r = m0 + wr + mi * 16 + rbase2 + j;
                float v = acc[mi][ni][j] + bv;
                if (res) v += res[(size_t)r * N + c];
                if (OUT_BF16) ((unsigned short*)Cp)[(size_t)r * N + c] = f2bf(v);
                else ((float*)Cp)[(size_t)r * N + c] = v;
            }
        }
    }
}

// ---------------- sparse attention v3: MFMA (verified r11) ----------------
#define KST 40    // Kt row stride (bf16)
#define VST 200   // Vt/P row stride (bf16)

__global__ __launch_bounds__(256, 4) void attn_kernel(const unsigned short* __restrict__ qkv,
                                                      const int* __restrict__ idx,
                                                      unsigned short* __restrict__ ao) {
    __shared__ int cols[NNZ];
    __shared__ unsigned short Kt[NNZ * KST];      // K [192 j][32 d]
    __shared__ unsigned short Vt[HD_ * VST];      // V^T [32 d][192 j]
    __shared__ unsigned short Pl[8 * VST];        // P [8 q][192 j]
    __shared__ float mpart[4][8];
    __shared__ float spart[4][8];

    int blk = blockIdx.x;
    int m = blk & 255, hh = (blk >> 8) & 7, b = blk >> 11;
    int tid = threadIdx.x;
    int w = tid >> 6;
    int gg = (tid >> 4) & 3;   // 16-lane group within wave
    int rl = tid & 15;

    if (tid < NNZ) cols[tid] = idx[m * NNZ + tid];
    __syncthreads();

#pragma unroll
    for (int k = 0; k < 3; k++) {
        int e = tid + 256 * k;
        int j = e % NNZ;
        int c = e / NNZ;
        size_t base = ((size_t)(cols[j] * 4 + b)) * 768 + hh * HD_ + c * 8;
        i32x4 kv = *(const i32x4*)&qkv[base + 256];
        *(i32x4*)&Kt[j * KST + c * 8] = kv;
        u16x8 vv = *(const u16x8*)&qkv[base + 512];
#pragma unroll
        for (int i2 = 0; i2 < 8; i2++)
            Vt[(c * 8 + i2) * VST + j] = vv[i2];
    }
    bf16x8 afq;
    if (rl < 8) {
        size_t qa = ((size_t)((m * 8 + rl) * 4 + b)) * 768 + hh * HD_ + gg * 8;
        afq = *(const bf16x8*)&qkv[qa];
    } else {
        afq = (bf16x8){0, 0, 0, 0, 0, 0, 0, 0};
    }
    __syncthreads();

    f32x4 acc[3];
#pragma unroll
    for (int t = 0; t < 3; t++) {
        int jt = w * 3 + t;
        bf16x8 bk = *(const bf16x8*)&Kt[(jt * 16 + rl) * KST + gg * 8];
        acc[t] = __builtin_amdgcn_mfma_f32_16x16x32_bf16(afq, bk,
                   (f32x4){0.f, 0.f, 0.f, 0.f}, 0, 0, 0);
    }

    float mv[4];
#pragma unroll
    for (int r = 0; r < 4; r++) {
        float mx = fmaxf(fmaxf(acc[0][r], acc[1][r]), acc[2][r]);
#pragma unroll
        for (int off = 1; off <= 8; off <<= 1) mx = fmaxf(mx, __shfl_xor(mx, off, 64));
        mv[r] = mx;
    }
    if (rl == 0 && gg < 2) {
#pragma unroll
        for (int r = 0; r < 4; r++) mpart[w][gg * 4 + r] = mv[r];
    }
    __syncthreads();
    int qbase = (gg & 1) * 4;
    float ev[3][4], sv[4];
#pragma unroll
    for (int r = 0; r < 4; r++) {
        float a = fmaxf(fmaxf(mpart[0][qbase + r], mpart[1][qbase + r]),
                        fmaxf(mpart[2][qbase + r], mpart[3][qbase + r]));
        float s = 0.f;
#pragma unroll
        for (int t = 0; t < 3; t++) {
            ev[t][r] = __expf((acc[t][r] - a) * 0.17677669529663687f);
            s += ev[t][r];
        }
#pragma unroll
        for (int off = 1; off <= 8; off <<= 1) s += __shfl_xor(s, off, 64);
        sv[r] = s;
    }
    if (rl == 0 && gg < 2) {
#pragma unroll
        for (int r = 0; r < 4; r++) spart[w][gg * 4 + r] = sv[r];
    }
    __syncthreads();
    if (gg < 2) {
#pragma unroll
        for (int r = 0; r < 4; r++) {
            float inv = 1.0f / (spart[0][qbase + r] + spart[1][qbase + r] +
                                spart[2][qbase + r] + spart[3][qbase + r]);
            int q = gg * 4 + r;
#pragma unroll
            for (int t = 0; t < 3; t++)
                Pl[q * VST + (w * 3 + t) * 16 + rl] = f2bf(ev[t][r] * inv);
        }
    }
    __syncthreads();

    if (w < 2) {
        f32x4 oacc = (f32x4){0.f, 0.f, 0.f, 0.f};
#pragma unroll
        for (int ks = 0; ks < 6; ks++) {
            bf16x8 ap = *(const bf16x8*)&Pl[(rl & 7) * VST + ks * 32 + gg * 8];
            bf16x8 bv = *(const bf16x8*)&Vt[(w * 16 + rl) * VST + ks * 32 + gg * 8];
            oacc = __builtin_amdgcn_mfma_f32_16x16x32_bf16(ap, bv, oacc, 0, 0, 0);
        }
        if (gg < 2) {
#pragma unroll
            for (int r = 0; r < 4; r++) {
                int q = gg * 4 + r;
                size_t oa = ((size_t)((m * 8 + q) * 4 + b)) * 256 + hh * HD_ + w * 16 + rl;
                ao[oa] = f2bf(oacc[r]);
            }
        }
    }
}

// ---------------- final LN + 2-class head ----------------
__global__ __launch_bounds__(256) void final_kernel(const float* __restrict__ h,
                                                    const float* __restrict__ g,
                                                    const float* __restrict__ b,
                                                    const float* __restrict__ wf,
                                                    const float* __restrict__ bf,
                                                    float* __restrict__ out) {
    int row = blockIdx.x * 4 + (threadIdx.x >> 6);
    int lane = threadIdx.x & 63;
    float4 v = *(const float4*)&h[(size_t)row * D_ + lane * 4];
    float s = v.x + v.y + v.z + v.w;
    float ss = v.x * v.x + v.y * v.y + v.z * v.z + v.w * v.w;
#pragma unroll
    for (int off = 32; off; off >>= 1) {
        s += __shfl_xor(s, off, 64);
        ss += __shfl_xor(ss, off, 64);
    }
    float mu = s * (1.0f / 256.0f);
    float var = ss * (1.0f / 256.0f) - mu * mu;
    float rstd = rsqrtf(var + 1e-5f);
    float4 gv = *(const float4*)&g[lane * 4];
    float4 bv = *(const float4*)&b[lane * 4];
    float o0 = (v.x - mu) * rstd * gv.x + bv.x;
    float o1 = (v.y - mu) * rstd * gv.y + bv.y;
    float o2 = (v.z - mu) * rstd * gv.z + bv.z;
    float o3 = (v.w - mu) * rstd * gv.w + bv.w;
    float4 w0 = *(const float4*)&wf[lane * 4];
    float4 w1 = *(const float4*)&wf[D_ + lane * 4];
    float a0 = o0 * w0.x + o1 * w0.y + o2 * w0.z + o3 * w0.w;
    float a1 = o0 * w1.x + o1 * w1.y + o2 * w1.z + o3 * w1.w;
#pragma unroll
    for (int off = 32; off; off >>= 1) {
        a0 += __shfl_xor(a0, off, 64);
        a1 += __shfl_xor(a1, off, 64);
    }
    if (lane == 0) {
        out[(size_t)row * 2 + 0] = a0 + bf[0];
        out[(size_t)row * 2 + 1] = a1 + bf[1];
    }
}

extern "C" void kernel_launch(void* const* d_in, const int* in_sizes, int n_in,
                              void* d_out, int out_size, void* d_ws, size_t ws_size,
                              hipStream_t stream) {
    const int* x = (const int*)d_in[0];
    const void* mask = d_in[1];
    const float* emb = (const float*)d_in[2];
    const float* ln1_g = (const float*)d_in[3];
    const float* ln1_b = (const float*)d_in[4];
    const float* in_w = (const float*)d_in[5];
    const float* in_b = (const float*)d_in[6];
    const float* out_w = (const float*)d_in[7];
    const float* out_b = (const float*)d_in[8];
    const float* ln2_g = (const float*)d_in[9];
    const float* ln2_b = (const float*)d_in[10];
    const float* w1 = (const float*)d_in[11];
    const float* b1 = (const float*)d_in[12];
    const float* w2 = (const float*)d_in[13];
    const float* b2 = (const float*)d_in[14];
    const float* lnf_g = (const float*)d_in[15];
    const float* lnf_b = (const float*)d_in[16];
    const float* wf = (const float*)d_in[17];
    const float* bfp = (const float*)d_in[18];
    float* out = (float*)d_out;

    const size_t MB = 1024 * 1024;
    char* ws = (char*)d_ws;
    int* idx = (int*)ws;
    int* flag = (int*)(ws + 786432);
    float* h = (float*)(ws + 1 * MB);
    unsigned short* o = (unsigned short*)(ws + 9 * MB);
    unsigned short* ao = o;
    float* h2 = (float*)(ws + 13 * MB);
    unsigned short* qkvb = (unsigned short*)(ws + 21 * MB);
    unsigned short* ff1 = (unsigned short*)(ws + 21 * MB);
    unsigned short* wbf = (unsigned short*)(ws + 37 * MB);
    unsigned short* in_w_bf = wbf;
    unsigned short* out_w_bf = wbf + 786432;
    unsigned short* w1_bf = wbf + 1048576;
    unsigned short* w2_bf = wbf + 2097152;

    hipMemsetAsync(flag, 0, sizeof(int), stream);
    detect_mask_kernel<<<16, 256, 0, stream>>>((const unsigned int*)mask, flag);
    build_idx_kernel<<<L_ * M_ / 4, 256, 0, stream>>>(mask, idx, flag);
    cvt_all_kernel<<<3072, 256, 0, stream>>>(in_w, out_w, w1, w2,
                                             in_w_bf, out_w_bf, w1_bf, w2_bf);
    embed_kernel<<<ROWS * (D_ / 2) / 256, 256, 0, stream>>>(x, emb, h);

    for (int l = 0; l < L_; l++) {
        ln_kernel<<<ROWS / 4, 256, 0, stream>>>(h, ln1_g + l * D_, ln1_b + l * D_, o);
        gemm_bf16_v2<1><<<dim3(768 / GBN, ROWS / GBM), 256, 0, stream>>>(
            o, in_w_bf + (size_t)l * 768 * D_, in_b + l * 768, nullptr, qkvb, 768, D_);
        attn_kernel<<<B_ * H_ * M_, 256, 0, stream>>>(qkvb, idx + l * M_ * NNZ, ao);
        gemm_bf16_v2<0><<<dim3(D_ / GBN, ROWS / GBM), 256, 0, stream>>>(
            ao, out_w_bf + (size_t)l * D_ * D_, out_b + l * D_, h, h2, D_, D_);
        ln_kernel<<<ROWS / 4, 256, 0, stream>>>(h2, ln2_g + l * D_, ln2_b + l * D_, o);
        gemm_bf16_v2<1><<<dim3(MLP_ / GBN, ROWS / GBM), 256, 0, stream>>>(
            o, w1_bf + (size_t)l * MLP_ * D_, b1 + l * MLP_, nullptr, ff1, MLP_, D_);
        gemm_bf16_v2<0><<<dim3(D_ / GBN, ROWS / GBM), 256, 0, stream>>>(
            ff1, w2_bf + (size_t)l * D_ * MLP_, b2 + l * D_, h, h, D_, MLP_);
    }
    final_kernel<<<ROWS / 4, 256, 0, stream>>>(h, lnf_g, lnf_b, wf, bfp, out);
}